// Round 18
// baseline (111.202 us; speedup 1.0000x reference)
//
#include <hip/hip_runtime.h>
#include <hip/hip_bf16.h>

typedef float f32x4 __attribute__((ext_vector_type(4)));
typedef short bf16x8 __attribute__((ext_vector_type(8)));

#define NPAIRS 16384
#define NROWS  32768
#define D      128
#define NCOL   512     // live gate cols (quad-interleaved: n' = 4*j + quad, j<128)
#define MROWS  64
#define FEW    5
#define NN     200
#define STEPS  4
#define JCH    50      // gather chunks per f (4 neighbors each: shorter chain, 2x TLP)
#define SA_STR 392     // sA row stride in shorts: q(128)|hq(128)|r(128)|pad(8)
#define SL     (NCOL * 32)
#define PANELB 96      // panel blocks (8 elems/thread)

// workspace offsets (bytes)
#define WS_WGP  0           // bf16 [12][512][32] = 393216
#define WS_BP   393216      // f32 [512]
#define WS_SG   395264      // f32 [5][128]
#define WS_PART 398336      // f32 [5*50][256] = 256000
#define WS_CTR  654336      // u32[5] per-f gather counters (memset 0 per call)

static __device__ __forceinline__ unsigned short f2bf(float f) {
  union { float f; unsigned u; } v; v.f = f;
  unsigned r = v.u + 0x7FFF + ((v.u >> 16) & 1);
  return (unsigned short)(r >> 16);
}
static __device__ __forceinline__ float bf2f(unsigned short h) {
  union { unsigned u; float f; } v; v.u = ((unsigned)h) << 16;
  return v.f;
}
// rcp-based activations (R10 win: v_rcp vs IEEE divide sequence)
static __device__ __forceinline__ float sigm(float x) {
  float e = __expf(-x);
  return __builtin_amdgcn_rcpf(1.0f + e);
}
static __device__ __forceinline__ float tanh_(float x) {
  float e = __expf(-2.0f * fabsf(x));
  float t = (1.0f - e) * __builtin_amdgcn_rcpf(1.0f + e);
  return x >= 0.f ? t : -t;
}

// ---- K1: panel + bias + gather + per-f last-block support stage-2 (R17 win).
// Gather chunks now 4 neighbors (was 8): halves the dependent-load chain,
// doubles gather TLP (250 blocks). Stage-2 LDS stays ~3.2KB. ----
__global__ void prep_gather_support(
    const float* __restrict__ wih, const float* __restrict__ whh,
    const float* __restrict__ bih, const float* __restrict__ bhh,
    const int* __restrict__ sp, const float* __restrict__ emb,
    const float* __restrict__ gw, const float* __restrict__ gb,
    const float* __restrict__ p1w, const float* __restrict__ p1b,
    const float* __restrict__ p2w, const float* __restrict__ p2b,
    const float* __restrict__ lng, const float* __restrict__ lnb,
    unsigned short* __restrict__ Wgp, float* __restrict__ bp,
    float* __restrict__ part, unsigned* __restrict__ ctr,
    float* __restrict__ sg_out) {
  __shared__ float S[256];
  __shared__ float sup[128];
  __shared__ float h1[256];
  __shared__ float xx[128];
  __shared__ float red[4];
  __shared__ unsigned donev;

  int b = blockIdx.x, tid = threadIdx.x;
  if (b < PANELB) {  // ---- weight panel (12 slices) + bias ----
    if (b < 2) {
      int bidx = b * 256 + tid;  // < 512
      int j = bidx >> 2, q = bidx & 3;
      bp[bidx] = bih[q * 256 + j] + bhh[q * 256 + j];
    }
    int base = (b * 256 + tid) * 8;  // < 196608
    bf16x8 pk;
#pragma unroll
    for (int e = 0; e < 8; ++e) {
      int idx = base + e;
      int ks = idx >> 14;
      int n  = (idx >> 5) & 511;
      int ki = idx & 31;
      int k  = ks * 32 + ki;
      int j = n >> 2, q = n & 3;
      int rowg = q * 256 + j;
      float v = (k < 128) ? wih[rowg * 128 + k] : whh[rowg * 256 + (k - 128)];
      pk[e] = (short)f2bf(v);
    }
    *(bf16x8*)(Wgp + base) = pk;
    return;
  }
  // ---- gather: one (f, cj) partial (4 neighbors) ----
  int g = b - PANELB;
  int f = g / JCH, cj = g % JCH;
  {
    int sel = tid >> 7, kk = tid & 127;
    float a = 0.f;
#pragma unroll
    for (int jj = 0; jj < 4; ++jj) {
      int sym = sp[(f * NN + cj * 4 + jj) * 2 + sel];
      a += emb[(size_t)sym * D + kk];
    }
    part[(f * JCH + cj) * 256 + tid] = a;
  }
  __syncthreads();          // all partial stores issued
  __threadfence();          // release to device scope
  if (tid == 0) donev = atomicAdd(&ctr[f], 1u);
  __syncthreads();
  if (donev != JCH - 1) return;  // only f's last gather block continues
  __threadfence();          // acquire: all of f's partials visible

  // ---- stage-2 for this f ----
  {
    float a = 0.f;
#pragma unroll
    for (int c = 0; c < JCH; ++c) a += part[(f * JCH + c) * 256 + tid];
    S[tid] = a;
  }
  __syncthreads();
  if (tid < 128) {  // sup = tanh((S @ gw.T + 200*gb)/5)
    const f32x4* wr = (const f32x4*)(gw + tid * 256);
    const f32x4* sr = (const f32x4*)S;
    float a = 0.f;
#pragma unroll 16
    for (int k4 = 0; k4 < 64; ++k4) {
      f32x4 w = wr[k4], s = sr[k4];
      a += w[0] * s[0] + w[1] * s[1] + w[2] * s[2] + w[3] * s[3];
    }
    sup[tid] = tanh_((a + 200.f * gb[tid]) * 0.2f);
  }
  __syncthreads();
  {  // h1 = relu(sup @ p1w.T + p1b)
    const f32x4* wr = (const f32x4*)(p1w + tid * 128);
    const f32x4* sr = (const f32x4*)sup;
    float a = p1b[tid];
#pragma unroll 16
    for (int k4 = 0; k4 < 32; ++k4) {
      f32x4 w = wr[k4], s = sr[k4];
      a += w[0] * s[0] + w[1] * s[1] + w[2] * s[2] + w[3] * s[3];
    }
    h1[tid] = fmaxf(a, 0.f);
  }
  __syncthreads();
  if (tid < 128) {  // xx = h1 @ p2w.T + p2b + sup
    const f32x4* wr = (const f32x4*)(p2w + tid * 256);
    const f32x4* sr = (const f32x4*)h1;
    float a = p2b[tid];
#pragma unroll 16
    for (int k4 = 0; k4 < 64; ++k4) {
      f32x4 w = wr[k4], s = sr[k4];
      a += w[0] * s[0] + w[1] * s[1] + w[2] * s[2] + w[3] * s[3];
    }
    xx[tid] = a + sup[tid];
  }
  __syncthreads();
  // LN: two-pass mean/var, shuffle-reduce over the 2 active waves
  if (tid < 128) {
    float s = xx[tid];
#pragma unroll
    for (int off = 1; off < 64; off <<= 1) s += __shfl_xor(s, off, 64);
    if ((tid & 63) == 0) red[tid >> 6] = s;
  }
  __syncthreads();
  float mu = (red[0] + red[1]) * (1.f / 128.f);
  if (tid < 128) {
    float d = xx[tid] - mu;
    float sq = d * d;
#pragma unroll
    for (int off = 1; off < 64; off <<= 1) sq += __shfl_xor(sq, off, 64);
    if ((tid & 63) == 0) red[2 + (tid >> 6)] = sq;
  }
  __syncthreads();
  if (tid < 128) {
    float var = (red[2] + red[3]) * (1.f / 128.f);
    float rs = rsqrtf(var + 1e-5f);
    sg_out[f * 128 + tid] = lng[tid] * (xx[tid] - mu) * rs + lnb[tid];
  }
}

// ---- K2: fused query path — R12 hot loop + bias-seeded acc (the single
// fused variable this round: MFMA C-in is additive, so acc starts at the
// bias vector and EW drops 4 adds/cell). Everything else byte-identical. ----
__global__ __launch_bounds__(512, 4) void fused_query(
    const int* __restrict__ qp, const float* __restrict__ emb,
    const unsigned short* __restrict__ Wgp, const float* __restrict__ bp,
    const float* __restrict__ sgw, float* __restrict__ out) {
  __shared__ __align__(16) unsigned short sA[MROWS][SA_STR];  // q|hq|r, 50176 B
  __shared__ unsigned short sC[MROWS][130];                   // c bf16, 16640 B
  __shared__ float sSg[FEW][132];
  __shared__ __align__(16) float sBias[NCOL];
  __shared__ float sMs[128];

  int tid = threadIdx.x;
  int w = tid >> 6, lane = tid & 63;
  int l15 = lane & 15, l4 = lane >> 4;
  int w16 = w * 16;
  int row0 = blockIdx.x * MROWS;

  for (int i = tid; i < MROWS * 32; i += 512) {
    int r = i >> 5, c4 = i & 31;
    int sym = qp[row0 + r];
    f32x4 v = *(const f32x4*)(emb + (size_t)sym * D + c4 * 4);
    int k = c4 * 4;
    sA[r][k + 0] = f2bf(v[0]); sA[r][k + 1] = f2bf(v[1]);
    sA[r][k + 2] = f2bf(v[2]); sA[r][k + 3] = f2bf(v[3]);
  }
  for (int i = tid; i < MROWS * 128; i += 512) sC[i >> 7][i & 127] = 0;
  for (int i = tid; i < FEW * 128; i += 512) sSg[i >> 7][i & 127] = sgw[i];
  if (tid < NCOL) sBias[tid] = bp[tid];
  __syncthreads();
  // mean_support from sSg; read only in the final phase (barrier-ordered)
  if (tid < 128) {
    float a = sSg[0][tid] + sSg[1][tid] + sSg[2][tid] + sSg[3][tid] + sSg[4][tid];
    sMs[tid] = a * 0.2f;
  }

  const unsigned short* wptr = Wgp + (size_t)(w * 64 + l15) * 32 + l4 * 8;

  for (int s = 0; s < STEPS; ++s) {
    // ---- gates GEMM: acc seeded with bias (C-in additive) ----
    f32x4 acc[4][4];
#pragma unroll
    for (int gt = 0; gt < 4; ++gt) {
      f32x4 bi = *(const f32x4*)&sBias[4 * (w16 + gt * 4 + l4)];
#pragma unroll
      for (int bt = 0; bt < 4; ++bt) acc[gt][bt] = bi;
    }
    int ksmax = (s == 0) ? 4 : 12;  // step 0: hq/r zero — only q contributes
    for (int ks = 0; ks < ksmax; ++ks) {
      const unsigned short* wk = wptr + (size_t)ks * SL;
      bf16x8 bfrag[4];
#pragma unroll
      for (int gt = 0; gt < 4; ++gt) bfrag[gt] = *(const bf16x8*)(wk + gt * 512);
      bf16x8 afrag[4];
#pragma unroll
      for (int bt = 0; bt < 4; ++bt)
        afrag[bt] = *(const bf16x8*)&sA[bt * 16 + l15][ks * 32 + l4 * 8];
#pragma unroll
      for (int gt = 0; gt < 4; ++gt)
#pragma unroll
        for (int bt = 0; bt < 4; ++bt)
          acc[gt][bt] = __builtin_amdgcn_mfma_f32_16x16x32_bf16(
              bfrag[gt], afrag[bt], acc[gt][bt], 0, 0, 0);
    }
    __syncthreads();  // GEMM reads of sA done before hq overwrite

    // ---- EW: acc f32x4 IS (i,f,g,o)+bias for (row=bt*16+l15, j=w16+gt*4+l4) ----
#pragma unroll
    for (int gt = 0; gt < 4; ++gt) {
      int j = w16 + gt * 4 + l4;
#pragma unroll
      for (int bt = 0; bt < 4; ++bt) {
        int row = bt * 16 + l15;
        f32x4 g = acc[gt][bt];
        float c_old = bf2f(sC[row][j]);
        float c_new = sigm(g[1]) * c_old + sigm(g[0]) * tanh_(g[2]);
        sC[row][j] = f2bf(c_new);
        float hl = sigm(g[3]) * tanh_(c_new);
        float hqv = bf2f(sA[row][j]) + hl;  // q + h_lstm
        sA[row][128 + j] = f2bf(hqv);
      }
    }
    __syncthreads();

    // ---- ATTN: logits + softmax + r (vectorized, chunk-swizzled) ----
    if (s < STEPS - 1) {
      int arow = tid >> 3, part = tid & 7;
      int ck = ((part + arow) & 7) * 16;
      bf16x8 h0 = *(const bf16x8*)&sA[arow][128 + ck];
      bf16x8 h1v8 = *(const bf16x8*)&sA[arow][128 + ck + 8];
      float hv[16];
#pragma unroll
      for (int e = 0; e < 8; ++e) {
        hv[e] = bf2f((unsigned short)h0[e]);
        hv[8 + e] = bf2f((unsigned short)h1v8[e]);
      }
      float lg[FEW];
#pragma unroll
      for (int ss = 0; ss < FEW; ++ss) {
        float a = 0.f;
#pragma unroll
        for (int e4 = 0; e4 < 4; ++e4) {
          f32x4 sv = *(const f32x4*)&sSg[ss][ck + e4 * 4];
          a += hv[e4 * 4 + 0] * sv[0] + hv[e4 * 4 + 1] * sv[1] +
               hv[e4 * 4 + 2] * sv[2] + hv[e4 * 4 + 3] * sv[3];
        }
        lg[ss] = a;
      }
#pragma unroll
      for (int off = 1; off < 8; off <<= 1)
#pragma unroll
        for (int ss = 0; ss < FEW; ++ss) lg[ss] += __shfl_xor(lg[ss], off, 64);
      float m = lg[0];
#pragma unroll
      for (int ss = 1; ss < FEW; ++ss) m = fmaxf(m, lg[ss]);
      float ev[FEW], tot = 0.f;
#pragma unroll
      for (int ss = 0; ss < FEW; ++ss) { ev[ss] = __expf(lg[ss] - m); tot += ev[ss]; }
      float inv = __builtin_amdgcn_rcpf(tot);
      bf16x8 r0, r1;
#pragma unroll
      for (int e = 0; e < 8; ++e) {
        int k0 = ck + e;
        int k1 = ck + 8 + e;
        float rv0 = 0.f, rv1 = 0.f;
#pragma unroll
        for (int ss = 0; ss < FEW; ++ss) {
          rv0 += ev[ss] * sSg[ss][k0];
          rv1 += ev[ss] * sSg[ss][k1];
        }
        r0[e] = (short)f2bf(rv0 * inv);
        r1[e] = (short)f2bf(rv1 * inv);
      }
      *(bf16x8*)&sA[arow][256 + ck] = r0;
      *(bf16x8*)&sA[arow][256 + ck + 8] = r1;
      __syncthreads();
    }
  }

  // ---- output: out[pair] = mean(hq[2p], hq[2p+1]) . mean_support ----
  int pair = tid >> 4, part = tid & 15;
  float accv = 0.f;
#pragma unroll
  for (int kk = 0; kk < 8; ++kk) {
    int k = part * 8 + kk;
    float h0 = bf2f(sA[2 * pair][128 + k]);
    float h1v = bf2f(sA[2 * pair + 1][128 + k]);
    accv += 0.5f * (h0 + h1v) * sMs[k];
  }
#pragma unroll
  for (int off = 1; off < 16; off <<= 1) accv += __shfl_xor(accv, off, 64);
  if (part == 0) out[blockIdx.x * 32 + pair] = accv;
}

extern "C" void kernel_launch(void* const* d_in, const int* in_sizes, int n_in,
                              void* d_out, int out_size, void* d_ws, size_t ws_size,
                              hipStream_t stream) {
  const int*   qp  = (const int*)d_in[0];
  const int*   sp  = (const int*)d_in[1];
  const float* emb = (const float*)d_in[2];
  const float* gw  = (const float*)d_in[3];
  const float* gb  = (const float*)d_in[4];
  const float* p1w = (const float*)d_in[5];
  const float* p1b = (const float*)d_in[6];
  const float* p2w = (const float*)d_in[7];
  const float* p2b = (const float*)d_in[8];
  const float* lng = (const float*)d_in[9];
  const float* lnb = (const float*)d_in[10];
  const float* wih = (const float*)d_in[11];
  const float* whh = (const float*)d_in[12];
  const float* bih = (const float*)d_in[13];
  const float* bhh = (const float*)d_in[14];
  char* ws = (char*)d_ws;
  unsigned short* Wgp = (unsigned short*)(ws + WS_WGP);
  float* bp   = (float*)(ws + WS_BP);
  float* sg   = (float*)(ws + WS_SG);
  float* part = (float*)(ws + WS_PART);
  unsigned* ctr = (unsigned*)(ws + WS_CTR);
  float* out  = (float*)d_out;

  hipMemsetAsync(ctr, 0, FEW * 4, stream);  // counters must be 0 every call
  hipLaunchKernelGGL(prep_gather_support, dim3(PANELB + FEW * JCH), dim3(256), 0, stream,
                     wih, whh, bih, bhh, sp, emb,
                     gw, gb, p1w, p1b, p2w, p2b, lng, lnb,
                     Wgp, bp, part, ctr, sg);
  hipLaunchKernelGGL(fused_query, dim3(NROWS / MROWS), dim3(512), 0, stream,
                     qp, emb, Wgp, bp, sg, out);
}

// Round 19
// 101.860 us; speedup vs baseline: 1.0917x; 1.0917x over previous
//
#include <hip/hip_runtime.h>
#include <hip/hip_bf16.h>

typedef float f32x4 __attribute__((ext_vector_type(4)));
typedef short bf16x8 __attribute__((ext_vector_type(8)));

#define NPAIRS 16384
#define NROWS  32768
#define D      128
#define NCOL   512     // live gate cols (quad-interleaved: n' = 4*j + quad, j<128)
#define MROWS  64
#define FEW    5
#define NN     200
#define STEPS  4
#define JCH    25      // gather chunks per f (8 neighbors each — R17 proven; JCH=50 regressed)
#define SA_STR 392     // sA row stride in shorts: q(128)|hq(128)|r(128)|pad(8)
#define SL     (NCOL * 32)
#define PANELB 96      // panel blocks (8 elems/thread)

// workspace offsets (bytes)
#define WS_WGP  0           // bf16 [12][512][32] = 393216
#define WS_BP   393216      // f32 [512]
#define WS_SG   395264      // f32 [5][128]
#define WS_PART 398336      // f32 [5*25][256] = 128000
#define WS_CTR  526336      // u32[5] per-f gather counters (memset 0 per call)

static __device__ __forceinline__ unsigned short f2bf(float f) {
  union { float f; unsigned u; } v; v.f = f;
  unsigned r = v.u + 0x7FFF + ((v.u >> 16) & 1);
  return (unsigned short)(r >> 16);
}
static __device__ __forceinline__ float bf2f(unsigned short h) {
  union { unsigned u; float f; } v; v.u = ((unsigned)h) << 16;
  return v.f;
}
// rcp-based activations (R10 win: v_rcp vs IEEE divide sequence)
static __device__ __forceinline__ float sigm(float x) {
  float e = __expf(-x);
  return __builtin_amdgcn_rcpf(1.0f + e);
}
static __device__ __forceinline__ float tanh_(float x) {
  float e = __expf(-2.0f * fabsf(x));
  float t = (1.0f - e) * __builtin_amdgcn_rcpf(1.0f + e);
  return x >= 0.f ? t : -t;
}

// ---- K1: panel + bias + gather + per-f last-block support stage-2 (R17 form:
// JCH=25, 8-neighbor chunks — the JCH=50 variant lengthened stage-2's serial
// reduce chain and regressed ~9us). Stage-2 LDS ~3.2KB (R14 lesson). ----
__global__ void prep_gather_support(
    const float* __restrict__ wih, const float* __restrict__ whh,
    const float* __restrict__ bih, const float* __restrict__ bhh,
    const int* __restrict__ sp, const float* __restrict__ emb,
    const float* __restrict__ gw, const float* __restrict__ gb,
    const float* __restrict__ p1w, const float* __restrict__ p1b,
    const float* __restrict__ p2w, const float* __restrict__ p2b,
    const float* __restrict__ lng, const float* __restrict__ lnb,
    unsigned short* __restrict__ Wgp, float* __restrict__ bp,
    float* __restrict__ part, unsigned* __restrict__ ctr,
    float* __restrict__ sg_out) {
  __shared__ float S[256];
  __shared__ float sup[128];
  __shared__ float h1[256];
  __shared__ float xx[128];
  __shared__ float red[4];
  __shared__ unsigned donev;

  int b = blockIdx.x, tid = threadIdx.x;
  if (b < PANELB) {  // ---- weight panel (12 slices) + bias ----
    if (b < 2) {
      int bidx = b * 256 + tid;  // < 512
      int j = bidx >> 2, q = bidx & 3;
      bp[bidx] = bih[q * 256 + j] + bhh[q * 256 + j];
    }
    int base = (b * 256 + tid) * 8;  // < 196608
    bf16x8 pk;
#pragma unroll
    for (int e = 0; e < 8; ++e) {
      int idx = base + e;
      int ks = idx >> 14;
      int n  = (idx >> 5) & 511;
      int ki = idx & 31;
      int k  = ks * 32 + ki;
      int j = n >> 2, q = n & 3;
      int rowg = q * 256 + j;
      float v = (k < 128) ? wih[rowg * 128 + k] : whh[rowg * 256 + (k - 128)];
      pk[e] = (short)f2bf(v);
    }
    *(bf16x8*)(Wgp + base) = pk;
    return;
  }
  // ---- gather: one (f, cj) partial (8 neighbors) ----
  int g = b - PANELB;
  int f = g / JCH, cj = g % JCH;
  {
    int sel = tid >> 7, kk = tid & 127;
    float a = 0.f;
#pragma unroll
    for (int jj = 0; jj < 8; ++jj) {
      int sym = sp[(f * NN + cj * 8 + jj) * 2 + sel];
      a += emb[(size_t)sym * D + kk];
    }
    part[(f * JCH + cj) * 256 + tid] = a;
  }
  __syncthreads();          // all partial stores issued
  __threadfence();          // release to device scope
  if (tid == 0) donev = atomicAdd(&ctr[f], 1u);
  __syncthreads();
  if (donev != JCH - 1) return;  // only f's last gather block continues
  __threadfence();          // acquire: all of f's partials visible

  // ---- stage-2 for this f ----
  {
    float a = 0.f;
#pragma unroll
    for (int c = 0; c < JCH; ++c) a += part[(f * JCH + c) * 256 + tid];
    S[tid] = a;
  }
  __syncthreads();
  if (tid < 128) {  // sup = tanh((S @ gw.T + 200*gb)/5)
    const f32x4* wr = (const f32x4*)(gw + tid * 256);
    const f32x4* sr = (const f32x4*)S;
    float a = 0.f;
#pragma unroll 16
    for (int k4 = 0; k4 < 64; ++k4) {
      f32x4 w = wr[k4], s = sr[k4];
      a += w[0] * s[0] + w[1] * s[1] + w[2] * s[2] + w[3] * s[3];
    }
    sup[tid] = tanh_((a + 200.f * gb[tid]) * 0.2f);
  }
  __syncthreads();
  {  // h1 = relu(sup @ p1w.T + p1b)
    const f32x4* wr = (const f32x4*)(p1w + tid * 128);
    const f32x4* sr = (const f32x4*)sup;
    float a = p1b[tid];
#pragma unroll 16
    for (int k4 = 0; k4 < 32; ++k4) {
      f32x4 w = wr[k4], s = sr[k4];
      a += w[0] * s[0] + w[1] * s[1] + w[2] * s[2] + w[3] * s[3];
    }
    h1[tid] = fmaxf(a, 0.f);
  }
  __syncthreads();
  if (tid < 128) {  // xx = h1 @ p2w.T + p2b + sup
    const f32x4* wr = (const f32x4*)(p2w + tid * 256);
    const f32x4* sr = (const f32x4*)h1;
    float a = p2b[tid];
#pragma unroll 16
    for (int k4 = 0; k4 < 64; ++k4) {
      f32x4 w = wr[k4], s = sr[k4];
      a += w[0] * s[0] + w[1] * s[1] + w[2] * s[2] + w[3] * s[3];
    }
    xx[tid] = a + sup[tid];
  }
  __syncthreads();
  // LN: two-pass mean/var, shuffle-reduce over the 2 active waves
  if (tid < 128) {
    float s = xx[tid];
#pragma unroll
    for (int off = 1; off < 64; off <<= 1) s += __shfl_xor(s, off, 64);
    if ((tid & 63) == 0) red[tid >> 6] = s;
  }
  __syncthreads();
  float mu = (red[0] + red[1]) * (1.f / 128.f);
  if (tid < 128) {
    float d = xx[tid] - mu;
    float sq = d * d;
#pragma unroll
    for (int off = 1; off < 64; off <<= 1) sq += __shfl_xor(sq, off, 64);
    if ((tid & 63) == 0) red[2 + (tid >> 6)] = sq;
  }
  __syncthreads();
  if (tid < 128) {
    float var = (red[2] + red[3]) * (1.f / 128.f);
    float rs = rsqrtf(var + 1e-5f);
    sg_out[f * 128 + tid] = lng[tid] * (xx[tid] - mu) * rs + lnb[tid];
  }
}

// ---- K2: fused query path — R12 hot loop + bias-seeded acc (R18-isolated win:
// fused 79.2->77.5us, VALUBusy 49->45.5%). Everything else byte-identical. ----
__global__ __launch_bounds__(512, 4) void fused_query(
    const int* __restrict__ qp, const float* __restrict__ emb,
    const unsigned short* __restrict__ Wgp, const float* __restrict__ bp,
    const float* __restrict__ sgw, float* __restrict__ out) {
  __shared__ __align__(16) unsigned short sA[MROWS][SA_STR];  // q|hq|r, 50176 B
  __shared__ unsigned short sC[MROWS][130];                   // c bf16, 16640 B
  __shared__ float sSg[FEW][132];
  __shared__ __align__(16) float sBias[NCOL];
  __shared__ float sMs[128];

  int tid = threadIdx.x;
  int w = tid >> 6, lane = tid & 63;
  int l15 = lane & 15, l4 = lane >> 4;
  int w16 = w * 16;
  int row0 = blockIdx.x * MROWS;

  for (int i = tid; i < MROWS * 32; i += 512) {
    int r = i >> 5, c4 = i & 31;
    int sym = qp[row0 + r];
    f32x4 v = *(const f32x4*)(emb + (size_t)sym * D + c4 * 4);
    int k = c4 * 4;
    sA[r][k + 0] = f2bf(v[0]); sA[r][k + 1] = f2bf(v[1]);
    sA[r][k + 2] = f2bf(v[2]); sA[r][k + 3] = f2bf(v[3]);
  }
  for (int i = tid; i < MROWS * 128; i += 512) sC[i >> 7][i & 127] = 0;
  for (int i = tid; i < FEW * 128; i += 512) sSg[i >> 7][i & 127] = sgw[i];
  if (tid < NCOL) sBias[tid] = bp[tid];
  __syncthreads();
  // mean_support from sSg; read only in the final phase (barrier-ordered)
  if (tid < 128) {
    float a = sSg[0][tid] + sSg[1][tid] + sSg[2][tid] + sSg[3][tid] + sSg[4][tid];
    sMs[tid] = a * 0.2f;
  }

  const unsigned short* wptr = Wgp + (size_t)(w * 64 + l15) * 32 + l4 * 8;

  for (int s = 0; s < STEPS; ++s) {
    // ---- gates GEMM: acc seeded with bias (C-in additive) ----
    f32x4 acc[4][4];
#pragma unroll
    for (int gt = 0; gt < 4; ++gt) {
      f32x4 bi = *(const f32x4*)&sBias[4 * (w16 + gt * 4 + l4)];
#pragma unroll
      for (int bt = 0; bt < 4; ++bt) acc[gt][bt] = bi;
    }
    int ksmax = (s == 0) ? 4 : 12;  // step 0: hq/r zero — only q contributes
    for (int ks = 0; ks < ksmax; ++ks) {
      const unsigned short* wk = wptr + (size_t)ks * SL;
      bf16x8 bfrag[4];
#pragma unroll
      for (int gt = 0; gt < 4; ++gt) bfrag[gt] = *(const bf16x8*)(wk + gt * 512);
      bf16x8 afrag[4];
#pragma unroll
      for (int bt = 0; bt < 4; ++bt)
        afrag[bt] = *(const bf16x8*)&sA[bt * 16 + l15][ks * 32 + l4 * 8];
#pragma unroll
      for (int gt = 0; gt < 4; ++gt)
#pragma unroll
        for (int bt = 0; bt < 4; ++bt)
          acc[gt][bt] = __builtin_amdgcn_mfma_f32_16x16x32_bf16(
              bfrag[gt], afrag[bt], acc[gt][bt], 0, 0, 0);
    }
    __syncthreads();  // GEMM reads of sA done before hq overwrite

    // ---- EW: acc f32x4 IS (i,f,g,o)+bias for (row=bt*16+l15, j=w16+gt*4+l4) ----
#pragma unroll
    for (int gt = 0; gt < 4; ++gt) {
      int j = w16 + gt * 4 + l4;
#pragma unroll
      for (int bt = 0; bt < 4; ++bt) {
        int row = bt * 16 + l15;
        f32x4 g = acc[gt][bt];
        float c_old = bf2f(sC[row][j]);
        float c_new = sigm(g[1]) * c_old + sigm(g[0]) * tanh_(g[2]);
        sC[row][j] = f2bf(c_new);
        float hl = sigm(g[3]) * tanh_(c_new);
        float hqv = bf2f(sA[row][j]) + hl;  // q + h_lstm
        sA[row][128 + j] = f2bf(hqv);
      }
    }
    __syncthreads();

    // ---- ATTN: logits + softmax + r (vectorized, chunk-swizzled) ----
    if (s < STEPS - 1) {
      int arow = tid >> 3, part = tid & 7;
      int ck = ((part + arow) & 7) * 16;
      bf16x8 h0 = *(const bf16x8*)&sA[arow][128 + ck];
      bf16x8 h1v8 = *(const bf16x8*)&sA[arow][128 + ck + 8];
      float hv[16];
#pragma unroll
      for (int e = 0; e < 8; ++e) {
        hv[e] = bf2f((unsigned short)h0[e]);
        hv[8 + e] = bf2f((unsigned short)h1v8[e]);
      }
      float lg[FEW];
#pragma unroll
      for (int ss = 0; ss < FEW; ++ss) {
        float a = 0.f;
#pragma unroll
        for (int e4 = 0; e4 < 4; ++e4) {
          f32x4 sv = *(const f32x4*)&sSg[ss][ck + e4 * 4];
          a += hv[e4 * 4 + 0] * sv[0] + hv[e4 * 4 + 1] * sv[1] +
               hv[e4 * 4 + 2] * sv[2] + hv[e4 * 4 + 3] * sv[3];
        }
        lg[ss] = a;
      }
#pragma unroll
      for (int off = 1; off < 8; off <<= 1)
#pragma unroll
        for (int ss = 0; ss < FEW; ++ss) lg[ss] += __shfl_xor(lg[ss], off, 64);
      float m = lg[0];
#pragma unroll
      for (int ss = 1; ss < FEW; ++ss) m = fmaxf(m, lg[ss]);
      float ev[FEW], tot = 0.f;
#pragma unroll
      for (int ss = 0; ss < FEW; ++ss) { ev[ss] = __expf(lg[ss] - m); tot += ev[ss]; }
      float inv = __builtin_amdgcn_rcpf(tot);
      bf16x8 r0, r1;
#pragma unroll
      for (int e = 0; e < 8; ++e) {
        int k0 = ck + e;
        int k1 = ck + 8 + e;
        float rv0 = 0.f, rv1 = 0.f;
#pragma unroll
        for (int ss = 0; ss < FEW; ++ss) {
          rv0 += ev[ss] * sSg[ss][k0];
          rv1 += ev[ss] * sSg[ss][k1];
        }
        r0[e] = (short)f2bf(rv0 * inv);
        r1[e] = (short)f2bf(rv1 * inv);
      }
      *(bf16x8*)&sA[arow][256 + ck] = r0;
      *(bf16x8*)&sA[arow][256 + ck + 8] = r1;
      __syncthreads();
    }
  }

  // ---- output: out[pair] = mean(hq[2p], hq[2p+1]) . mean_support ----
  int pair = tid >> 4, part = tid & 15;
  float accv = 0.f;
#pragma unroll
  for (int kk = 0; kk < 8; ++kk) {
    int k = part * 8 + kk;
    float h0 = bf2f(sA[2 * pair][128 + k]);
    float h1v = bf2f(sA[2 * pair + 1][128 + k]);
    accv += 0.5f * (h0 + h1v) * sMs[k];
  }
#pragma unroll
  for (int off = 1; off < 16; off <<= 1) accv += __shfl_xor(accv, off, 64);
  if (part == 0) out[blockIdx.x * 32 + pair] = accv;
}

extern "C" void kernel_launch(void* const* d_in, const int* in_sizes, int n_in,
                              void* d_out, int out_size, void* d_ws, size_t ws_size,
                              hipStream_t stream) {
  const int*   qp  = (const int*)d_in[0];
  const int*   sp  = (const int*)d_in[1];
  const float* emb = (const float*)d_in[2];
  const float* gw  = (const float*)d_in[3];
  const float* gb  = (const float*)d_in[4];
  const float* p1w = (const float*)d_in[5];
  const float* p1b = (const float*)d_in[6];
  const float* p2w = (const float*)d_in[7];
  const float* p2b = (const float*)d_in[8];
  const float* lng = (const float*)d_in[9];
  const float* lnb = (const float*)d_in[10];
  const float* wih = (const float*)d_in[11];
  const float* whh = (const float*)d_in[12];
  const float* bih = (const float*)d_in[13];
  const float* bhh = (const float*)d_in[14];
  char* ws = (char*)d_ws;
  unsigned short* Wgp = (unsigned short*)(ws + WS_WGP);
  float* bp   = (float*)(ws + WS_BP);
  float* sg   = (float*)(ws + WS_SG);
  float* part = (float*)(ws + WS_PART);
  unsigned* ctr = (unsigned*)(ws + WS_CTR);
  float* out  = (float*)d_out;

  hipMemsetAsync(ctr, 0, FEW * 4, stream);  // counters must be 0 every call
  hipLaunchKernelGGL(prep_gather_support, dim3(PANELB + FEW * JCH), dim3(256), 0, stream,
                     wih, whh, bih, bhh, sp, emb,
                     gw, gb, p1w, p1b, p2w, p2b, lng, lnb,
                     Wgp, bp, part, ctr, sg);
  hipLaunchKernelGGL(fused_query, dim3(NROWS / MROWS), dim3(512), 0, stream,
                     qp, emb, Wgp, bp, sg, out);
}

// Round 22
// 100.567 us; speedup vs baseline: 1.1057x; 1.0129x over previous
//
#include <hip/hip_runtime.h>
#include <hip/hip_bf16.h>

typedef float f32x4 __attribute__((ext_vector_type(4)));
typedef short bf16x8 __attribute__((ext_vector_type(8)));

#define NPAIRS 16384
#define NROWS  32768
#define D      128
#define NCOL   512     // live gate cols (quad-interleaved: n' = 4*j + quad, j<128)
#define MROWS  64
#define FEW    5
#define NN     200
#define STEPS  4
#define JCH    25      // gather chunks per f (8 neighbors each — R17/R19 proven)
#define SA_STR 392     // sA row stride in shorts: q(128)|hq(128)|r(128)|pad(8)
#define SL     (NCOL * 32)
#define PANELB 96      // panel blocks (8 elems/thread)

// workspace offsets (bytes)
#define WS_WGP  0           // bf16 [12][512][32] = 393216
#define WS_BP   393216      // f32 [512]
#define WS_SG   395264      // f32 [5][128]
#define WS_PART 398336      // f32 [5*25][256] = 128000
#define WS_CTR  526336      // u32[5] per-f gather counters (memset 0 per call)

static __device__ __forceinline__ unsigned short f2bf(float f) {
  union { float f; unsigned u; } v; v.f = f;
  unsigned r = v.u + 0x7FFF + ((v.u >> 16) & 1);
  return (unsigned short)(r >> 16);
}
static __device__ __forceinline__ float bf2f(unsigned short h) {
  union { unsigned u; float f; } v; v.u = ((unsigned)h) << 16;
  return v.f;
}
// rcp-based activations (R10 win: v_rcp vs IEEE divide sequence)
static __device__ __forceinline__ float sigm(float x) {
  float e = __expf(-x);
  return __builtin_amdgcn_rcpf(1.0f + e);
}
static __device__ __forceinline__ float tanh_(float x) {
  float e = __expf(-2.0f * fabsf(x));
  float t = (1.0f - e) * __builtin_amdgcn_rcpf(1.0f + e);
  return x >= 0.f ? t : -t;
}

// ---- K1: panel + bias + gather + per-f last-block support stage-2 (R17 form:
// JCH=25, 8-neighbor chunks). Stage-2 LDS ~3.2KB (R14 lesson). ----
__global__ void prep_gather_support(
    const float* __restrict__ wih, const float* __restrict__ whh,
    const float* __restrict__ bih, const float* __restrict__ bhh,
    const int* __restrict__ sp, const float* __restrict__ emb,
    const float* __restrict__ gw, const float* __restrict__ gb,
    const float* __restrict__ p1w, const float* __restrict__ p1b,
    const float* __restrict__ p2w, const float* __restrict__ p2b,
    const float* __restrict__ lng, const float* __restrict__ lnb,
    unsigned short* __restrict__ Wgp, float* __restrict__ bp,
    float* __restrict__ part, unsigned* __restrict__ ctr,
    float* __restrict__ sg_out) {
  __shared__ float S[256];
  __shared__ float sup[128];
  __shared__ float h1[256];
  __shared__ float xx[128];
  __shared__ float red[4];
  __shared__ unsigned donev;

  int b = blockIdx.x, tid = threadIdx.x;
  if (b < PANELB) {  // ---- weight panel (12 slices) + bias ----
    if (b < 2) {
      int bidx = b * 256 + tid;  // < 512
      int j = bidx >> 2, q = bidx & 3;
      bp[bidx] = bih[q * 256 + j] + bhh[q * 256 + j];
    }
    int base = (b * 256 + tid) * 8;  // < 196608
    bf16x8 pk;
#pragma unroll
    for (int e = 0; e < 8; ++e) {
      int idx = base + e;
      int ks = idx >> 14;
      int n  = (idx >> 5) & 511;
      int ki = idx & 31;
      int k  = ks * 32 + ki;
      int j = n >> 2, q = n & 3;
      int rowg = q * 256 + j;
      float v = (k < 128) ? wih[rowg * 128 + k] : whh[rowg * 256 + (k - 128)];
      pk[e] = (short)f2bf(v);
    }
    *(bf16x8*)(Wgp + base) = pk;
    return;
  }
  // ---- gather: one (f, cj) partial (8 neighbors) ----
  int g = b - PANELB;
  int f = g / JCH, cj = g % JCH;
  {
    int sel = tid >> 7, kk = tid & 127;
    float a = 0.f;
#pragma unroll
    for (int jj = 0; jj < 8; ++jj) {
      int sym = sp[(f * NN + cj * 8 + jj) * 2 + sel];
      a += emb[(size_t)sym * D + kk];
    }
    part[(f * JCH + cj) * 256 + tid] = a;
  }
  __syncthreads();          // all partial stores issued
  __threadfence();          // release to device scope
  if (tid == 0) donev = atomicAdd(&ctr[f], 1u);
  __syncthreads();
  if (donev != JCH - 1) return;  // only f's last gather block continues
  __threadfence();          // acquire: all of f's partials visible

  // ---- stage-2 for this f ----
  {
    float a = 0.f;
#pragma unroll
    for (int c = 0; c < JCH; ++c) a += part[(f * JCH + c) * 256 + tid];
    S[tid] = a;
  }
  __syncthreads();
  if (tid < 128) {  // sup = tanh((S @ gw.T + 200*gb)/5)
    const f32x4* wr = (const f32x4*)(gw + tid * 256);
    const f32x4* sr = (const f32x4*)S;
    float a = 0.f;
#pragma unroll 16
    for (int k4 = 0; k4 < 64; ++k4) {
      f32x4 w = wr[k4], s = sr[k4];
      a += w[0] * s[0] + w[1] * s[1] + w[2] * s[2] + w[3] * s[3];
    }
    sup[tid] = tanh_((a + 200.f * gb[tid]) * 0.2f);
  }
  __syncthreads();
  {  // h1 = relu(sup @ p1w.T + p1b)
    const f32x4* wr = (const f32x4*)(p1w + tid * 128);
    const f32x4* sr = (const f32x4*)sup;
    float a = p1b[tid];
#pragma unroll 16
    for (int k4 = 0; k4 < 32; ++k4) {
      f32x4 w = wr[k4], s = sr[k4];
      a += w[0] * s[0] + w[1] * s[1] + w[2] * s[2] + w[3] * s[3];
    }
    h1[tid] = fmaxf(a, 0.f);
  }
  __syncthreads();
  if (tid < 128) {  // xx = h1 @ p2w.T + p2b + sup
    const f32x4* wr = (const f32x4*)(p2w + tid * 256);
    const f32x4* sr = (const f32x4*)h1;
    float a = p2b[tid];
#pragma unroll 16
    for (int k4 = 0; k4 < 64; ++k4) {
      f32x4 w = wr[k4], s = sr[k4];
      a += w[0] * s[0] + w[1] * s[1] + w[2] * s[2] + w[3] * s[3];
    }
    xx[tid] = a + sup[tid];
  }
  __syncthreads();
  // LN: two-pass mean/var, shuffle-reduce over the 2 active waves
  if (tid < 128) {
    float s = xx[tid];
#pragma unroll
    for (int off = 1; off < 64; off <<= 1) s += __shfl_xor(s, off, 64);
    if ((tid & 63) == 0) red[tid >> 6] = s;
  }
  __syncthreads();
  float mu = (red[0] + red[1]) * (1.f / 128.f);
  if (tid < 128) {
    float d = xx[tid] - mu;
    float sq = d * d;
#pragma unroll
    for (int off = 1; off < 64; off <<= 1) sq += __shfl_xor(sq, off, 64);
    if ((tid & 63) == 0) red[2 + (tid >> 6)] = sq;
  }
  __syncthreads();
  if (tid < 128) {
    float var = (red[2] + red[3]) * (1.f / 128.f);
    float rs = rsqrtf(var + 1e-5f);
    sg_out[f * 128 + tid] = lng[tid] * (xx[tid] - mu) * rs + lnb[tid];
  }
}

// ---- K2: fused query path — R12 hot loop + bias-seeded acc (R18-isolated win:
// fused 79.2->77.5us, VALUBusy 49->45.5%). Everything else byte-identical. ----
__global__ __launch_bounds__(512, 4) void fused_query(
    const int* __restrict__ qp, const float* __restrict__ emb,
    const unsigned short* __restrict__ Wgp, const float* __restrict__ bp,
    const float* __restrict__ sgw, float* __restrict__ out) {
  __shared__ __align__(16) unsigned short sA[MROWS][SA_STR];  // q|hq|r, 50176 B
  __shared__ unsigned short sC[MROWS][130];                   // c bf16, 16640 B
  __shared__ float sSg[FEW][132];
  __shared__ __align__(16) float sBias[NCOL];
  __shared__ float sMs[128];

  int tid = threadIdx.x;
  int w = tid >> 6, lane = tid & 63;
  int l15 = lane & 15, l4 = lane >> 4;
  int w16 = w * 16;
  int row0 = blockIdx.x * MROWS;

  for (int i = tid; i < MROWS * 32; i += 512) {
    int r = i >> 5, c4 = i & 31;
    int sym = qp[row0 + r];
    f32x4 v = *(const f32x4*)(emb + (size_t)sym * D + c4 * 4);
    int k = c4 * 4;
    sA[r][k + 0] = f2bf(v[0]); sA[r][k + 1] = f2bf(v[1]);
    sA[r][k + 2] = f2bf(v[2]); sA[r][k + 3] = f2bf(v[3]);
  }
  for (int i = tid; i < MROWS * 128; i += 512) sC[i >> 7][i & 127] = 0;
  for (int i = tid; i < FEW * 128; i += 512) sSg[i >> 7][i & 127] = sgw[i];
  if (tid < NCOL) sBias[tid] = bp[tid];
  __syncthreads();
  // mean_support from sSg; read only in the final phase (barrier-ordered)
  if (tid < 128) {
    float a = sSg[0][tid] + sSg[1][tid] + sSg[2][tid] + sSg[3][tid] + sSg[4][tid];
    sMs[tid] = a * 0.2f;
  }

  const unsigned short* wptr = Wgp + (size_t)(w * 64 + l15) * 32 + l4 * 8;

  for (int s = 0; s < STEPS; ++s) {
    // ---- gates GEMM: acc seeded with bias (C-in additive) ----
    f32x4 acc[4][4];
#pragma unroll
    for (int gt = 0; gt < 4; ++gt) {
      f32x4 bi = *(const f32x4*)&sBias[4 * (w16 + gt * 4 + l4)];
#pragma unroll
      for (int bt = 0; bt < 4; ++bt) acc[gt][bt] = bi;
    }
    int ksmax = (s == 0) ? 4 : 12;  // step 0: hq/r zero — only q contributes
    for (int ks = 0; ks < ksmax; ++ks) {
      const unsigned short* wk = wptr + (size_t)ks * SL;
      bf16x8 bfrag[4];
#pragma unroll
      for (int gt = 0; gt < 4; ++gt) bfrag[gt] = *(const bf16x8*)(wk + gt * 512);
      bf16x8 afrag[4];
#pragma unroll
      for (int bt = 0; bt < 4; ++bt)
        afrag[bt] = *(const bf16x8*)&sA[bt * 16 + l15][ks * 32 + l4 * 8];
#pragma unroll
      for (int gt = 0; gt < 4; ++gt)
#pragma unroll
        for (int bt = 0; bt < 4; ++bt)
          acc[gt][bt] = __builtin_amdgcn_mfma_f32_16x16x32_bf16(
              bfrag[gt], afrag[bt], acc[gt][bt], 0, 0, 0);
    }
    __syncthreads();  // GEMM reads of sA done before hq overwrite

    // ---- EW: acc f32x4 IS (i,f,g,o)+bias for (row=bt*16+l15, j=w16+gt*4+l4) ----
#pragma unroll
    for (int gt = 0; gt < 4; ++gt) {
      int j = w16 + gt * 4 + l4;
#pragma unroll
      for (int bt = 0; bt < 4; ++bt) {
        int row = bt * 16 + l15;
        f32x4 g = acc[gt][bt];
        float c_old = bf2f(sC[row][j]);
        float c_new = sigm(g[1]) * c_old + sigm(g[0]) * tanh_(g[2]);
        sC[row][j] = f2bf(c_new);
        float hl = sigm(g[3]) * tanh_(c_new);
        float hqv = bf2f(sA[row][j]) + hl;  // q + h_lstm
        sA[row][128 + j] = f2bf(hqv);
      }
    }
    __syncthreads();

    // ---- ATTN: logits + softmax + r (vectorized, chunk-swizzled) ----
    if (s < STEPS - 1) {
      int arow = tid >> 3, part = tid & 7;
      int ck = ((part + arow) & 7) * 16;
      bf16x8 h0 = *(const bf16x8*)&sA[arow][128 + ck];
      bf16x8 h1v8 = *(const bf16x8*)&sA[arow][128 + ck + 8];
      float hv[16];
#pragma unroll
      for (int e = 0; e < 8; ++e) {
        hv[e] = bf2f((unsigned short)h0[e]);
        hv[8 + e] = bf2f((unsigned short)h1v8[e]);
      }
      float lg[FEW];
#pragma unroll
      for (int ss = 0; ss < FEW; ++ss) {
        float a = 0.f;
#pragma unroll
        for (int e4 = 0; e4 < 4; ++e4) {
          f32x4 sv = *(const f32x4*)&sSg[ss][ck + e4 * 4];
          a += hv[e4 * 4 + 0] * sv[0] + hv[e4 * 4 + 1] * sv[1] +
               hv[e4 * 4 + 2] * sv[2] + hv[e4 * 4 + 3] * sv[3];
        }
        lg[ss] = a;
      }
#pragma unroll
      for (int off = 1; off < 8; off <<= 1)
#pragma unroll
        for (int ss = 0; ss < FEW; ++ss) lg[ss] += __shfl_xor(lg[ss], off, 64);
      float m = lg[0];
#pragma unroll
      for (int ss = 1; ss < FEW; ++ss) m = fmaxf(m, lg[ss]);
      float ev[FEW], tot = 0.f;
#pragma unroll
      for (int ss = 0; ss < FEW; ++ss) { ev[ss] = __expf(lg[ss] - m); tot += ev[ss]; }
      float inv = __builtin_amdgcn_rcpf(tot);
      bf16x8 r0, r1;
#pragma unroll
      for (int e = 0; e < 8; ++e) {
        int k0 = ck + e;
        int k1 = ck + 8 + e;
        float rv0 = 0.f, rv1 = 0.f;
#pragma unroll
        for (int ss = 0; ss < FEW; ++ss) {
          rv0 += ev[ss] * sSg[ss][k0];
          rv1 += ev[ss] * sSg[ss][k1];
        }
        r0[e] = (short)f2bf(rv0 * inv);
        r1[e] = (short)f2bf(rv1 * inv);
      }
      *(bf16x8*)&sA[arow][256 + ck] = r0;
      *(bf16x8*)&sA[arow][256 + ck + 8] = r1;
      __syncthreads();
    }
  }

  // ---- output: out[pair] = mean(hq[2p], hq[2p+1]) . mean_support ----
  int pair = tid >> 4, part = tid & 15;
  float accv = 0.f;
#pragma unroll
  for (int kk = 0; kk < 8; ++kk) {
    int k = part * 8 + kk;
    float h0 = bf2f(sA[2 * pair][128 + k]);
    float h1v = bf2f(sA[2 * pair + 1][128 + k]);
    accv += 0.5f * (h0 + h1v) * sMs[k];
  }
#pragma unroll
  for (int off = 1; off < 16; off <<= 1) accv += __shfl_xor(accv, off, 64);
  if (part == 0) out[blockIdx.x * 32 + pair] = accv;
}

extern "C" void kernel_launch(void* const* d_in, const int* in_sizes, int n_in,
                              void* d_out, int out_size, void* d_ws, size_t ws_size,
                              hipStream_t stream) {
  const int*   qp  = (const int*)d_in[0];
  const int*   sp  = (const int*)d_in[1];
  const float* emb = (const float*)d_in[2];
  const float* gw  = (const float*)d_in[3];
  const float* gb  = (const float*)d_in[4];
  const float* p1w = (const float*)d_in[5];
  const float* p1b = (const float*)d_in[6];
  const float* p2w = (const float*)d_in[7];
  const float* p2b = (const float*)d_in[8];
  const float* lng = (const float*)d_in[9];
  const float* lnb = (const float*)d_in[10];
  const float* wih = (const float*)d_in[11];
  const float* whh = (const float*)d_in[12];
  const float* bih = (const float*)d_in[13];
  const float* bhh = (const float*)d_in[14];
  char* ws = (char*)d_ws;
  unsigned short* Wgp = (unsigned short*)(ws + WS_WGP);
  float* bp   = (float*)(ws + WS_BP);
  float* sg   = (float*)(ws + WS_SG);
  float* part = (float*)(ws + WS_PART);
  unsigned* ctr = (unsigned*)(ws + WS_CTR);
  float* out  = (float*)d_out;

  hipMemsetAsync(ctr, 0, FEW * 4, stream);  // counters must be 0 every call
  hipLaunchKernelGGL(prep_gather_support, dim3(PANELB + FEW * JCH), dim3(256), 0, stream,
                     wih, whh, bih, bhh, sp, emb,
                     gw, gb, p1w, p1b, p2w, p2b, lng, lnb,
                     Wgp, bp, part, ctr, sg);
  hipLaunchKernelGGL(fused_query, dim3(NROWS / MROWS), dim3(512), 0, stream,
                     qp, emb, Wgp, bp, sg, out);
}